// Round 18
// baseline (3603.457 us; speedup 1.0000x reference)
//
#include <hip/hip_runtime.h>
#include <hip/hip_bf16.h>
#include <cstdint>
#include <cstddef>

// ---------------------------------------------------------------------------
// DisentangledMultiHeadAttention: B=8, H=2, T=2048, D=2048, C=4096
// R18 = R15 structure (best: 2697us) with mfma_f32_32x32x16_bf16, kh-OUTER
// accumulation order. R10's 32x32 collapse traced to kh-INNERMOST: two
// back-to-back dependent MFMAs per accumulator (full-latency stall per
// pair). kh-outer gives reuse distance of 8 MFMAs. MFMA pipe per slab:
// 1242 -> 1024 cyc (m119 constants); LDS traffic unchanged.
//   256x256 tile, 8 waves (2M x 4N; wave = 128x64 out), 4-slot K=32 LDS
//   ring (128KB), single barrier/slab, counted vmcnt(4), register prefetch
//   of slab p+1 frags, SGB interleave 12x{1 DS_READ,1 MFMA}+{4 MFMA},
//   frag-major 1KB LDS units (0 bank conflicts, R10-validated staging,
//   R7-validated 32x32 C/D layout), T1 XCD swizzle, T5 setprio, plain
//   stores, merged 3-way W cvt (R15 launcher).
// v stored TRANSPOSED so PV is NT; softmax emits bf16 probs for PV.
// ---------------------------------------------------------------------------

typedef short short8_t __attribute__((ext_vector_type(8)));
typedef float f32x4   __attribute__((ext_vector_type(4)));
typedef float f32x16  __attribute__((ext_vector_type(16)));

__device__ __forceinline__ short f2bf(float f) {
  unsigned u = __builtin_bit_cast(unsigned, f);
  u = (u + 0x7FFFu + ((u >> 16) & 1u)) >> 16;   // round-to-nearest-even
  return (short)u;
}

__device__ __forceinline__ short8_t cvt8(f32x4 a, f32x4 b) {
  short8_t r;
  r[0] = f2bf(a[0]); r[1] = f2bf(a[1]); r[2] = f2bf(a[2]); r[3] = f2bf(a[3]);
  r[4] = f2bf(b[0]); r[5] = f2bf(b[1]); r[6] = f2bf(b[2]); r[7] = f2bf(b[3]);
  return r;
}

__device__ __forceinline__ void gld_lds16(const void* g, void* l) {
  __builtin_amdgcn_global_load_lds(
      (const __attribute__((address_space(1))) void*)g,
      (__attribute__((address_space(3))) void*)l, 16, 0, 0);
}

// fp32 -> bf16 bulk convert; NT loads (fp32 source dead after this)
__global__ __launch_bounds__(256)
void cvt_f32_bf16(const float* __restrict__ src, short* __restrict__ dst, int n8) {
  for (int i = blockIdx.x * blockDim.x + threadIdx.x; i < n8;
       i += gridDim.x * blockDim.x) {
    const f32x4* p = (const f32x4*)(src + (size_t)i * 8);
    f32x4 a = __builtin_nontemporal_load(p);
    f32x4 b = __builtin_nontemporal_load(p + 1);
    *(short8_t*)(dst + (size_t)i * 8) = cvt8(a, b);
  }
}

// three W matrices -> one contiguous bf16 block (single launch)
__global__ __launch_bounds__(256)
void cvt3_f32_bf16(const float* __restrict__ s0, const float* __restrict__ s1,
                   const float* __restrict__ s2, short* __restrict__ dst,
                   int n8each) {
  const int total = 3 * n8each;
  for (int i = blockIdx.x * blockDim.x + threadIdx.x; i < total;
       i += gridDim.x * blockDim.x) {
    const int which = i / n8each;
    const int off   = i - which * n8each;
    const float* s  = (which == 0) ? s0 : (which == 1) ? s1 : s2;
    const f32x4* p = (const f32x4*)(s + (size_t)off * 8);
    f32x4 a = __builtin_nontemporal_load(p);
    f32x4 b = __builtin_nontemporal_load(p + 1);
    *(short8_t*)(dst + (size_t)i * 8) = cvt8(a, b);
  }
}

// MODE 0: q/k proj  C=bf16 (b,h,t,d)                 K=4096
// MODE 2: v proj    C=bf16 (b,h,d,s) [transposed]    K=4096
// MODE 3: scores    C=f32 scale+bias -> attn (d_out) K=2048, batched z
// MODE 4: PV        C=bf16 (b*T+t, h*D+d)            K=2048, batched z
// MODE 5: out proj  C=f32 y (d_out)                  K=4096
template<int MODE>
__global__ __launch_bounds__(512, 2)
void gemm256(const short* __restrict__ Ag, const short* __restrict__ Bg,
             void* __restrict__ Cg, const float* __restrict__ bias) {
  constexpr int K  = (MODE == 3 || MODE == 4) ? 2048 : 4096;
  constexpr int NS = K / 32;   // K-slabs (even, >= 64)

  // ring: 4 slots x 32KB; per slot: 16 A units (1KB: 32 rows x 16 k bf16),
  // unit index = mi*2+kh; then 16 B units likewise.
  __shared__ short lds[65536];

  const int tid = threadIdx.x;

  // T1: bijective XCD swizzle (gridDim.x = 1024, divisible by 8)
  const int bid = blockIdx.x;
  const int id  = (bid & 7) * (gridDim.x >> 3) + (bid >> 3);

  int m0, n0, z = 0;
  size_t aoff = 0, boff = 0;
  if constexpr (MODE == 3 || MODE == 4) {
    z  = id >> 6;                       // 16 batches
    m0 = ((id >> 3) & 7) << 8;          // 8 m-tiles
    n0 = (id & 7) << 8;                 // 8 n-tiles
    aoff = boff = (size_t)z << 22;
  } else {
    m0 = (id >> 4) << 8;                // 64 m-tiles
    n0 = (id & 15) << 8;                // 16 n-tiles (n fastest: A-panel reuse)
  }

  const int l = tid & 63;
  const int w = tid >> 6;               // wave id 0..7

  // ---- staging (frag-major, 32x32x16 operand layout; R10-validated):
  //      unit (mi,kh): lane l holds (row mi*32+(l&31), k kh*16+(l>>5)*8..+7).
  //      Wave w stages A units (w,0),(w,1) and B units (w,0),(w,1) per slab.
  const int srow = l & 31;
  const int sk8  = (l >> 5) * 8;
  const short* ApS = Ag + aoff + (size_t)(m0 + 32 * w + srow) * K + sk8;
  const short* BpS = Bg + boff + (size_t)(n0 + 32 * w + srow) * K + sk8;
  short* lA0 = &lds[(2 * w + 0) * 512 + l * 8];
  short* lA1 = &lds[(2 * w + 1) * 512 + l * 8];
  short* lB0 = &lds[8192 + (2 * w + 0) * 512 + l * 8];
  short* lB1 = &lds[8192 + (2 * w + 1) * 512 + l * 8];

  auto STAGE = [&](int t) {
    const int s = (t & 3) << 14;
    const int k = t * 32;
    gld_lds16(ApS + k,      lA0 + s);
    gld_lds16(ApS + k + 16, lA1 + s);
    gld_lds16(BpS + k,      lB0 + s);
    gld_lds16(BpS + k + 16, lB1 + s);
  };

  // ---- fragment read bases: wave w -> m-group g=w>>2 (128 rows),
  //      n-group h=w&3 (64 cols). A frags mi=g*4+i (i 0..3), B nj=h*2+j.
  const int g  = w >> 2;
  const int h  = w & 3;
  const int l8 = l * 8;

  f32x16 acc[4][2] = {};
  short8_t fA[4][2], fB[2][2], gA[4][2], gB[2][2];

  auto LOADFRAG = [&](const short* sl, short8_t (&A)[4][2], short8_t (&B)[2][2]) {
#pragma unroll
    for (int i = 0; i < 4; ++i)
#pragma unroll
      for (int kh = 0; kh < 2; ++kh)
        A[i][kh] = *(const short8_t*)&sl[((g * 4 + i) * 2 + kh) * 512 + l8];
#pragma unroll
    for (int j = 0; j < 2; ++j)
#pragma unroll
      for (int kh = 0; kh < 2; ++kh)
        B[j][kh] = *(const short8_t*)&sl[8192 + ((h * 2 + j) * 2 + kh) * 512 + l8];
  };

  // kh-OUTER MFMA order: all 8 accs touched in kh=0 before kh=1 ->
  // dependent-reuse distance 8 MFMAs (R10's kh-inner bug fixed).
  auto MFMAS = [&](short8_t (&cA)[4][2], short8_t (&cB)[2][2]) {
#pragma unroll
    for (int kh = 0; kh < 2; ++kh)
#pragma unroll
      for (int i = 0; i < 4; ++i)
#pragma unroll
        for (int j = 0; j < 2; ++j)
          acc[i][j] = __builtin_amdgcn_mfma_f32_32x32x16_bf16(
              cA[i][kh], cB[j][kh], acc[i][j], 0, 0, 0);
  };

  // Branch-free interleaved phase (valid for p <= NS-4).
  auto phaseF = [&](int p, short8_t (&cA)[4][2], short8_t (&cB)[2][2],
                    short8_t (&nA)[4][2], short8_t (&nB)[2][2]) {
    asm volatile("s_waitcnt vmcnt(4)" ::: "memory");   // slab p+1 landed
    __builtin_amdgcn_s_barrier();
    STAGE(p + 3);                      // slot (p-1)&3: WAR-safe (R8 proof)
    const short* sl = &lds[((p + 1) & 3) << 14];
    __builtin_amdgcn_s_setprio(1);
    LOADFRAG(sl, nA, nB);              // 12 ds_read_b128 (slab p+1)
    MFMAS(cA, cB);                     // 16 MFMA (slab p)
    // T19: 12 x {1 DS_READ, 1 MFMA} then {4 MFMA} tail
    // (LDS 1152 cyc vs MFMA 1024 cyc per slab -> ~1:1 rate match).
#pragma unroll
    for (int u = 0; u < 12; ++u) {
      __builtin_amdgcn_sched_group_barrier(0x100, 1, 0);
      __builtin_amdgcn_sched_group_barrier(0x008, 1, 0);
    }
    __builtin_amdgcn_sched_group_barrier(0x008, 4, 0);
    __builtin_amdgcn_s_setprio(0);
  };

  // Generic (branchy) phase for the 4 tail phases.
  auto phaseT = [&](int p, short8_t (&cA)[4][2], short8_t (&cB)[2][2],
                    short8_t (&nA)[4][2], short8_t (&nB)[2][2]) {
    if (p + 2 < NS) {
      asm volatile("s_waitcnt vmcnt(4)" ::: "memory");
    } else {
      asm volatile("s_waitcnt vmcnt(0)" ::: "memory");
    }
    __builtin_amdgcn_s_barrier();
    if (p + 3 < NS) STAGE(p + 3);
    if (p + 1 < NS) LOADFRAG(&lds[((p + 1) & 3) << 14], nA, nB);
    __builtin_amdgcn_s_setprio(1);
    MFMAS(cA, cB);
    __builtin_amdgcn_s_setprio(0);
  };

  STAGE(0); STAGE(1); STAGE(2);
  asm volatile("s_waitcnt vmcnt(8)" ::: "memory");   // slab 0 landed
  __builtin_amdgcn_s_barrier();
  LOADFRAG(&lds[0], fA, fB);

  int p = 0;
  for (; p < NS - 4; p += 2) {
    phaseF(p,     fA, fB, gA, gB);
    phaseF(p + 1, gA, gB, fA, fB);
  }
  // tail: phases NS-4 .. NS-1 (NS even -> cur = fA at NS-4)
  phaseT(NS - 4, fA, fB, gA, gB);
  phaseT(NS - 3, gA, gB, fA, fB);
  phaseT(NS - 2, fA, fB, gA, gB);
  phaseT(NS - 1, gA, gB, fA, fB);

  // ---- epilogue (plain stores): 32x32 C/D (R7-validated):
  //      col = lane&31, row = (r&3) + 8*(r>>2) + 4*(lane>>5)
  const int col = l & 31;
  const int rhi = (l >> 5) * 4;
#pragma unroll
  for (int i = 0; i < 4; ++i) {
#pragma unroll
    for (int j = 0; j < 2; ++j) {
#pragma unroll
      for (int r = 0; r < 16; ++r) {
        const int row = (r & 3) + 8 * (r >> 2) + rhi;
        const int gm  = m0 + g * 128 + i * 32 + row;
        const int gn  = n0 + h * 64 + j * 32 + col;
        const float v = acc[i][j][r];
        if constexpr (MODE == 0) {
          short* dst = (short*)Cg;
          const int bh = ((gm >> 11) << 1) + (gn >> 11);
          dst[((size_t)bh << 22) + ((size_t)(gm & 2047) << 11) + (gn & 2047)] = f2bf(v);
        } else if constexpr (MODE == 2) {
          short* dst = (short*)Cg;
          const int bh = ((gm >> 11) << 1) + (gn >> 11);
          dst[((size_t)bh << 22) + ((size_t)(gn & 2047) << 11) + (gm & 2047)] = f2bf(v);
        } else if constexpr (MODE == 3) {
          float* dst = (float*)Cg;
          const float sv = v * 0.022097086912079608f + bias[((z & 1) << 11) + gn];
          dst[((size_t)z << 22) + ((size_t)gm << 11) + gn] = sv;
        } else if constexpr (MODE == 4) {
          short* dst = (short*)Cg;
          const size_t orow = ((size_t)(z >> 1) << 11) + gm;
          dst[(orow << 12) + ((size_t)(z & 1) << 11) + gn] = f2bf(v);
        } else {
          float* dst = (float*)Cg;
          dst[(size_t)gm * 4096 + gn] = v;
        }
      }
    }
  }
}

// row softmax in place (fp32, 2048 wide) + bf16 copy for the PV GEMM.
__global__ __launch_bounds__(256)
void softmax_rows(float* __restrict__ attn, short* __restrict__ outb) {
  float* row  = attn + ((size_t)blockIdx.x << 11);
  short* rowb = outb + ((size_t)blockIdx.x << 11);
  const int tid = threadIdx.x;

  f32x4 v0 = *(const f32x4*)(row + tid * 8);
  f32x4 v1 = *(const f32x4*)(row + tid * 8 + 4);

  float m = fmaxf(fmaxf(fmaxf(v0[0], v0[1]), fmaxf(v0[2], v0[3])),
                  fmaxf(fmaxf(v1[0], v1[1]), fmaxf(v1[2], v1[3])));
#pragma unroll
  for (int off = 1; off < 64; off <<= 1) m = fmaxf(m, __shfl_xor(m, off));

  __shared__ float redm[4];
  __shared__ float reds[4];
  if ((tid & 63) == 0) redm[tid >> 6] = m;
  __syncthreads();
  m = fmaxf(fmaxf(redm[0], redm[1]), fmaxf(redm[2], redm[3]));

  float e[8];
#pragma unroll
  for (int i = 0; i < 4; ++i) e[i]     = expf(v0[i] - m);
#pragma unroll
  for (int i = 0; i < 4; ++i) e[4 + i] = expf(v1[i] - m);
  float s = 0.f;
#pragma unroll
  for (int i = 0; i < 8; ++i) s += e[i];
#pragma unroll
  for (int off = 1; off < 64; off <<= 1) s += __shfl_xor(s, off);
  if ((tid & 63) == 0) reds[tid >> 6] = s;
  __syncthreads();
  s = reds[0] + reds[1] + reds[2] + reds[3];

  const float inv = 1.0f / s;
  f32x4 o0, o1;
#pragma unroll
  for (int i = 0; i < 4; ++i) { o0[i] = e[i] * inv; o1[i] = e[4 + i] * inv; }
  *(f32x4*)(row + tid * 8)     = o0;
  *(f32x4*)(row + tid * 8 + 4) = o1;
  *(short8_t*)(rowb + tid * 8) = cvt8(o0, o1);
}

extern "C" void kernel_launch(void* const* d_in, const int* in_sizes, int n_in,
                              void* d_out, int out_size, void* d_ws, size_t ws_size,
                              hipStream_t stream) {
  const float* x  = (const float*)d_in[0];
  const float* Wq = (const float*)d_in[1];
  const float* Wk = (const float*)d_in[2];
  const float* Wv = (const float*)d_in[3];
  const float* Wo = (const float*)d_in[4];
  const float* pb = (const float*)d_in[5];

  float* y_out = (float*)d_out;                       // 8*2048*4096 f32
  float* attn  = y_out + (size_t)8 * 2048 * 4096;     // 16*2048*2048 f32

  const size_t NEED = 4ull * 67108864ull * 2ull;      // 512 MB
  if (ws_size < NEED) return;
  short* buf0 = (short*)d_ws;
  short* buf1 = buf0 + 67108864;
  short* buf2 = buf1 + 67108864;
  short* buf3 = buf2 + 67108864;

  short* xb      = buf0;             // x bf16 (16384 x 4096)
  short* qb      = buf1;             // (b,h,t,d)
  short* kb      = buf2;             // (b,h,t,d)
  short* vtb     = buf3;             // (b,h,d,s)
  short* wob     = buf0;             // Wo bf16 (reuses xb after projections)
  short* attn_bf = buf1;             // bf16 probs (reuses qb after scores)
  short* yb      = buf2;             // attn@v bf16 (reuses kb after scores)
  short* wqkv    = (short*)attn;     // [Wq;Wk;Wv] bf16 (96 MB) in d_out attn
                                     // region (dead until scores GEMM)

  const dim3 blk512(512);
  const dim3 blk(256);
  const dim3 gcv(2048);
  const dim3 g1k(1024);

  cvt_f32_bf16<<<gcv, blk, 0, stream>>>(x, xb, 67108864 / 8);
  cvt3_f32_bf16<<<gcv, blk, 0, stream>>>(Wq, Wk, Wv, wqkv, 16777216 / 8);

  gemm256<0><<<g1k, blk512, 0, stream>>>(xb, wqkv,                qb,  nullptr);
  gemm256<0><<<g1k, blk512, 0, stream>>>(xb, wqkv + 16777216,     kb,  nullptr);
  gemm256<2><<<g1k, blk512, 0, stream>>>(xb, wqkv + 2 * 16777216, vtb, nullptr);

  cvt_f32_bf16<<<gcv, blk, 0, stream>>>(Wo, wob, 16777216 / 8);  // x dead now

  gemm256<3><<<g1k, blk512, 0, stream>>>(qb, kb, attn, pb);
  softmax_rows<<<dim3(32768), blk, 0, stream>>>(attn, attn_bf);
  gemm256<4><<<g1k, blk512, 0, stream>>>(attn_bf, vtb, yb, nullptr);
  gemm256<5><<<g1k, blk512, 0, stream>>>(yb, wob, y_out, nullptr);
}

// Round 19
// 2703.969 us; speedup vs baseline: 1.3327x; 1.3327x over previous
//
#include <hip/hip_runtime.h>
#include <hip/hip_bf16.h>
#include <cstdint>
#include <cstddef>

// ---------------------------------------------------------------------------
// DisentangledMultiHeadAttention: B=8, H=2, T=2048, D=2048, C=4096
// FINAL (R15 revert; measured optimum over 18 rounds: 2697us).
// GEMM engine: 256x256 tile, 8 waves (2Mx4N), 16x16x32 bf16 MFMA, 4-slot
// K=32 LDS ring (128KB), single barrier/slab, counted vmcnt(4) (never 0
// mid-loop), register prefetch of slab p+1 frags, SGB fine interleave
// 12x{1 DS_READ, 2 MFMA}+{8 MFMA}, frag-major 1KB LDS units (0 bank
// conflicts both sides), T1 XCD swizzle, T5 setprio, plain stores.
// Bracketed-and-rejected: 32x32 MFMA (R10/R18, both orders), 128^2 tile
// (R16: HBM-bound), 4/16-wave variants (R9/R11), 8-phase ports (R5/R6),
// NT stores (write amplification), fused QKV (L3 thrash).
// Measured: proj GEMM ~525us (~1030 TF, 41% of dense peak), MfmaUtil 55%.
// v stored TRANSPOSED so PV is NT; softmax emits bf16 probs for PV.
// ---------------------------------------------------------------------------

typedef short short8_t __attribute__((ext_vector_type(8)));
typedef float f32x4   __attribute__((ext_vector_type(4)));

__device__ __forceinline__ short f2bf(float f) {
  unsigned u = __builtin_bit_cast(unsigned, f);
  u = (u + 0x7FFFu + ((u >> 16) & 1u)) >> 16;   // round-to-nearest-even
  return (short)u;
}

__device__ __forceinline__ short8_t cvt8(f32x4 a, f32x4 b) {
  short8_t r;
  r[0] = f2bf(a[0]); r[1] = f2bf(a[1]); r[2] = f2bf(a[2]); r[3] = f2bf(a[3]);
  r[4] = f2bf(b[0]); r[5] = f2bf(b[1]); r[6] = f2bf(b[2]); r[7] = f2bf(b[3]);
  return r;
}

__device__ __forceinline__ void gld_lds16(const void* g, void* l) {
  __builtin_amdgcn_global_load_lds(
      (const __attribute__((address_space(1))) void*)g,
      (__attribute__((address_space(3))) void*)l, 16, 0, 0);
}

// fp32 -> bf16 bulk convert; NT loads (fp32 source dead after this)
__global__ __launch_bounds__(256)
void cvt_f32_bf16(const float* __restrict__ src, short* __restrict__ dst, int n8) {
  for (int i = blockIdx.x * blockDim.x + threadIdx.x; i < n8;
       i += gridDim.x * blockDim.x) {
    const f32x4* p = (const f32x4*)(src + (size_t)i * 8);
    f32x4 a = __builtin_nontemporal_load(p);
    f32x4 b = __builtin_nontemporal_load(p + 1);
    *(short8_t*)(dst + (size_t)i * 8) = cvt8(a, b);
  }
}

// three W matrices -> one contiguous bf16 block (single launch)
__global__ __launch_bounds__(256)
void cvt3_f32_bf16(const float* __restrict__ s0, const float* __restrict__ s1,
                   const float* __restrict__ s2, short* __restrict__ dst,
                   int n8each) {
  const int total = 3 * n8each;
  for (int i = blockIdx.x * blockDim.x + threadIdx.x; i < total;
       i += gridDim.x * blockDim.x) {
    const int which = i / n8each;
    const int off   = i - which * n8each;
    const float* s  = (which == 0) ? s0 : (which == 1) ? s1 : s2;
    const f32x4* p = (const f32x4*)(s + (size_t)off * 8);
    f32x4 a = __builtin_nontemporal_load(p);
    f32x4 b = __builtin_nontemporal_load(p + 1);
    *(short8_t*)(dst + (size_t)i * 8) = cvt8(a, b);
  }
}

// MODE 0: q/k proj  C=bf16 (b,h,t,d)                 K=4096
// MODE 2: v proj    C=bf16 (b,h,d,s) [transposed]    K=4096
// MODE 3: scores    C=f32 scale+bias -> attn (d_out) K=2048, batched z
// MODE 4: PV        C=bf16 (b*T+t, h*D+d)            K=2048, batched z
// MODE 5: out proj  C=f32 y (d_out)                  K=4096
template<int MODE>
__global__ __launch_bounds__(512, 2)
void gemm256(const short* __restrict__ Ag, const short* __restrict__ Bg,
             void* __restrict__ Cg, const float* __restrict__ bias) {
  constexpr int K  = (MODE == 3 || MODE == 4) ? 2048 : 4096;
  constexpr int NS = K / 32;   // K-slabs (even, >= 64)

  __shared__ short lds[65536];  // 4 slots x (A 8192 + B 8192 shorts) = 128KB

  const int tid = threadIdx.x;

  // T1: bijective XCD swizzle (gridDim.x = 1024, divisible by 8)
  const int bid = blockIdx.x;
  const int id  = (bid & 7) * (gridDim.x >> 3) + (bid >> 3);

  int m0, n0, z = 0;
  size_t aoff = 0, boff = 0;
  if constexpr (MODE == 3 || MODE == 4) {
    z  = id >> 6;                       // 16 batches
    m0 = ((id >> 3) & 7) << 8;          // 8 m-tiles
    n0 = (id & 7) << 8;                 // 8 n-tiles
    aoff = boff = (size_t)z << 22;
  } else {
    m0 = (id >> 4) << 8;                // 64 m-tiles
    n0 = (id & 15) << 8;                // 16 n-tiles (n fastest: A-panel reuse)
  }

  // ---- staging: slab = 1024 chunks of 16B; thread does chunks tid, tid+512
  //      per operand. chunk c -> row c>>2, phys slot c&3; global source slot
  //      = phys ^ ((row>>1)&3)  [inverse swizzle, both-sides rule].
  const int r0 = tid >> 2;
  const int qs = ((tid & 3) ^ ((r0 >> 1) & 3)) << 3;
  const short* Ap0 = Ag + aoff + (size_t)(m0 + r0) * K + qs;
  const short* Ap1 = Ap0 + (size_t)128 * K;
  const short* Bp0 = Bg + boff + (size_t)(n0 + r0) * K + qs;
  const short* Bp1 = Bp0 + (size_t)128 * K;
  short* la0 = &lds[0]    + tid * 8;
  short* la1 = la0 + 4096;
  short* lb0 = &lds[8192] + tid * 8;
  short* lb1 = lb0 + 4096;

  auto STAGE = [&](int t) {
    const int s = (t & 3) * 16384;
    const int k = t * 32;
    gld_lds16(Ap0 + k, la0 + s);
    gld_lds16(Ap1 + k, la1 + s);
    gld_lds16(Bp0 + k, lb0 + s);
    gld_lds16(Bp1 + k, lb1 + s);
  };

  // ---- fragment read setup (2-way-conflict swizzled; measured 0) ----
  const int l  = tid & 63;
  const int fr = l & 15;
  const int kq = l >> 4;
  const int wm = (tid >> 8) << 7;         // wave m offset: 0 / 128
  const int wn = ((tid >> 6) & 3) << 6;   // wave n offset: 0/64/128/192
  const int slotP = (kq ^ ((fr >> 1) & 3)) << 3;
  const int aB = (wm + fr) * 32 + slotP;
  const int bB = 8192 + (wn + fr) * 32 + slotP;

  f32x4 acc[8][4] = {};
  short8_t fA[8], fB[4], gA[8], gB[4];

  // Branch-free interleaved phase (valid for p <= NS-4): reads of slab p+1
  // interleaved 1:2 with slab-p MFMAs via sched_group_barrier.
  auto phaseF = [&](int p, short8_t (&cA)[8], short8_t (&cB)[4],
                    short8_t (&nA)[8], short8_t (&nB)[4]) {
    asm volatile("s_waitcnt vmcnt(4)" ::: "memory");   // slab p+1 landed
    __builtin_amdgcn_s_barrier();
    STAGE(p + 3);
    const short* sl = &lds[((p + 1) & 3) * 16384];
    __builtin_amdgcn_s_setprio(1);
#pragma unroll
    for (int gq = 0; gq < 4; ++gq) {
      nA[2 * gq]     = *(const short8_t*)&sl[aB + (2 * gq) * 512];
      nA[2 * gq + 1] = *(const short8_t*)&sl[aB + (2 * gq + 1) * 512];
      nB[gq]         = *(const short8_t*)&sl[bB + gq * 512];
#pragma unroll
      for (int mm = 0; mm < 2; ++mm)
#pragma unroll
        for (int n = 0; n < 4; ++n)
          acc[2 * gq + mm][n] = __builtin_amdgcn_mfma_f32_16x16x32_bf16(
              cA[2 * gq + mm], cB[n], acc[2 * gq + mm][n], 0, 0, 0);
    }
    // T19 fine-grain: 12 x {1 DS_READ, 2 MFMA} then {8 MFMA} tail.
    // (masks: DS_READ=0x100, MFMA=0x8); other classes unconstrained.
#pragma unroll
    for (int u = 0; u < 12; ++u) {
      __builtin_amdgcn_sched_group_barrier(0x100, 1, 0);
      __builtin_amdgcn_sched_group_barrier(0x008, 2, 0);
    }
    __builtin_amdgcn_sched_group_barrier(0x008, 8, 0);
    __builtin_amdgcn_s_setprio(0);
  };

  // Generic (branchy) phase -- used for the 4 tail phases.
  auto phaseT = [&](int p, short8_t (&cA)[8], short8_t (&cB)[4],
                    short8_t (&nA)[8], short8_t (&nB)[4]) {
    if (p + 2 < NS) {
      asm volatile("s_waitcnt vmcnt(4)" ::: "memory");
    } else {
      asm volatile("s_waitcnt vmcnt(0)" ::: "memory");
    }
    __builtin_amdgcn_s_barrier();
    if (p + 3 < NS) STAGE(p + 3);
    if (p + 1 < NS) {
      const short* sl = &lds[((p + 1) & 3) * 16384];
#pragma unroll
      for (int m = 0; m < 8; ++m) nA[m] = *(const short8_t*)&sl[aB + m * 512];
#pragma unroll
      for (int n = 0; n < 4; ++n) nB[n] = *(const short8_t*)&sl[bB + n * 512];
    }
    __builtin_amdgcn_s_setprio(1);
#pragma unroll
    for (int m = 0; m < 8; ++m)
#pragma unroll
      for (int n = 0; n < 4; ++n)
        acc[m][n] = __builtin_amdgcn_mfma_f32_16x16x32_bf16(cA[m], cB[n], acc[m][n], 0, 0, 0);
    __builtin_amdgcn_s_setprio(0);
  };

  STAGE(0); STAGE(1); STAGE(2);
  asm volatile("s_waitcnt vmcnt(8)" ::: "memory");   // slab 0 landed
  __builtin_amdgcn_s_barrier();
  {
    const short* sl = &lds[0];
#pragma unroll
    for (int m = 0; m < 8; ++m) fA[m] = *(const short8_t*)&sl[aB + m * 512];
#pragma unroll
    for (int n = 0; n < 4; ++n) fB[n] = *(const short8_t*)&sl[bB + n * 512];
  }

  int p = 0;
  for (; p < NS - 4; p += 2) {
    phaseF(p,     fA, fB, gA, gB);
    phaseF(p + 1, gA, gB, fA, fB);
  }
  // tail: phases NS-4 .. NS-1 (NS even -> cur = fA at NS-4)
  phaseT(NS - 4, fA, fB, gA, gB);
  phaseT(NS - 3, gA, gB, fA, fB);
  phaseT(NS - 2, fA, fB, gA, gB);
  phaseT(NS - 1, gA, gB, fA, fB);

  // ---- epilogue (plain stores): C/D layout col=lane&15, row=(l>>4)*4+r ----
#pragma unroll
  for (int m = 0; m < 8; ++m) {
#pragma unroll
    for (int n = 0; n < 4; ++n) {
#pragma unroll
      for (int r = 0; r < 4; ++r) {
        const int gm = m0 + wm + m * 16 + kq * 4 + r;
        const int gn = n0 + wn + n * 16 + fr;
        const float v = acc[m][n][r];
        if constexpr (MODE == 0) {
          short* dst = (short*)Cg;
          const int bh = ((gm >> 11) << 1) + (gn >> 11);
          dst[((size_t)bh << 22) + ((size_t)(gm & 2047) << 11) + (gn & 2047)] = f2bf(v);
        } else if constexpr (MODE == 2) {
          short* dst = (short*)Cg;
          const int bh = ((gm >> 11) << 1) + (gn >> 11);
          dst[((size_t)bh << 22) + ((size_t)(gn & 2047) << 11) + (gm & 2047)] = f2bf(v);
        } else if constexpr (MODE == 3) {
          float* dst = (float*)Cg;
          const float sv = v * 0.022097086912079608f + bias[((z & 1) << 11) + gn];
          dst[((size_t)z << 22) + ((size_t)gm << 11) + gn] = sv;
        } else if constexpr (MODE == 4) {
          short* dst = (short*)Cg;
          const size_t row = ((size_t)(z >> 1) << 11) + gm;
          dst[(row << 12) + ((size_t)(z & 1) << 11) + gn] = f2bf(v);
        } else {
          float* dst = (float*)Cg;
          dst[(size_t)gm * 4096 + gn] = v;
        }
      }
    }
  }
}

// row softmax in place (fp32, 2048 wide) + bf16 copy for the PV GEMM.
__global__ __launch_bounds__(256)
void softmax_rows(float* __restrict__ attn, short* __restrict__ outb) {
  float* row  = attn + ((size_t)blockIdx.x << 11);
  short* rowb = outb + ((size_t)blockIdx.x << 11);
  const int tid = threadIdx.x;

  f32x4 v0 = *(const f32x4*)(row + tid * 8);
  f32x4 v1 = *(const f32x4*)(row + tid * 8 + 4);

  float m = fmaxf(fmaxf(fmaxf(v0[0], v0[1]), fmaxf(v0[2], v0[3])),
                  fmaxf(fmaxf(v1[0], v1[1]), fmaxf(v1[2], v1[3])));
#pragma unroll
  for (int off = 1; off < 64; off <<= 1) m = fmaxf(m, __shfl_xor(m, off));

  __shared__ float redm[4];
  __shared__ float reds[4];
  if ((tid & 63) == 0) redm[tid >> 6] = m;
  __syncthreads();
  m = fmaxf(fmaxf(redm[0], redm[1]), fmaxf(redm[2], redm[3]));

  float e[8];
#pragma unroll
  for (int i = 0; i < 4; ++i) e[i]     = expf(v0[i] - m);
#pragma unroll
  for (int i = 0; i < 4; ++i) e[4 + i] = expf(v1[i] - m);
  float s = 0.f;
#pragma unroll
  for (int i = 0; i < 8; ++i) s += e[i];
#pragma unroll
  for (int off = 1; off < 64; off <<= 1) s += __shfl_xor(s, off);
  if ((tid & 63) == 0) reds[tid >> 6] = s;
  __syncthreads();
  s = reds[0] + reds[1] + reds[2] + reds[3];

  const float inv = 1.0f / s;
  f32x4 o0, o1;
#pragma unroll
  for (int i = 0; i < 4; ++i) { o0[i] = e[i] * inv; o1[i] = e[4 + i] * inv; }
  *(f32x4*)(row + tid * 8)     = o0;
  *(f32x4*)(row + tid * 8 + 4) = o1;
  *(short8_t*)(rowb + tid * 8) = cvt8(o0, o1);
}

extern "C" void kernel_launch(void* const* d_in, const int* in_sizes, int n_in,
                              void* d_out, int out_size, void* d_ws, size_t ws_size,
                              hipStream_t stream) {
  const float* x  = (const float*)d_in[0];
  const float* Wq = (const float*)d_in[1];
  const float* Wk = (const float*)d_in[2];
  const float* Wv = (const float*)d_in[3];
  const float* Wo = (const float*)d_in[4];
  const float* pb = (const float*)d_in[5];

  float* y_out = (float*)d_out;                       // 8*2048*4096 f32
  float* attn  = y_out + (size_t)8 * 2048 * 4096;     // 16*2048*2048 f32

  const size_t NEED = 4ull * 67108864ull * 2ull;      // 512 MB
  if (ws_size < NEED) return;
  short* buf0 = (short*)d_ws;
  short* buf1 = buf0 + 67108864;
  short* buf2 = buf1 + 67108864;
  short* buf3 = buf2 + 67108864;

  short* xb      = buf0;             // x bf16 (16384 x 4096)
  short* qb      = buf1;             // (b,h,t,d)
  short* kb      = buf2;             // (b,h,t,d)
  short* vtb     = buf3;             // (b,h,d,s)
  short* wob     = buf0;             // Wo bf16 (reuses xb after projections)
  short* attn_bf = buf1;             // bf16 probs (reuses qb after scores)
  short* yb      = buf2;             // attn@v bf16 (reuses kb after scores)
  short* wqkv    = (short*)attn;     // [Wq;Wk;Wv] bf16 (96 MB) in d_out attn
                                     // region (dead until scores GEMM)

  const dim3 blk512(512);
  const dim3 blk(256);
  const dim3 gcv(2048);
  const dim3 g1k(1024);

  cvt_f32_bf16<<<gcv, blk, 0, stream>>>(x, xb, 67108864 / 8);
  cvt3_f32_bf16<<<gcv, blk, 0, stream>>>(Wq, Wk, Wv, wqkv, 16777216 / 8);

  gemm256<0><<<g1k, blk512, 0, stream>>>(xb, wqkv,                qb,  nullptr);
  gemm256<0><<<g1k, blk512, 0, stream>>>(xb, wqkv + 16777216,     kb,  nullptr);
  gemm256<2><<<g1k, blk512, 0, stream>>>(xb, wqkv + 2 * 16777216, vtb, nullptr);

  cvt_f32_bf16<<<gcv, blk, 0, stream>>>(Wo, wob, 16777216 / 8);  // x dead now

  gemm256<3><<<g1k, blk512, 0, stream>>>(qb, kb, attn, pb);
  softmax_rows<<<dim3(32768), blk, 0, stream>>>(attn, attn_bf);
  gemm256<4><<<g1k, blk512, 0, stream>>>(attn_bf, vtb, yb, nullptr);
  gemm256<5><<<g1k, blk512, 0, stream>>>(yb, wob, y_out, nullptr);
}

// Round 20
// 2675.717 us; speedup vs baseline: 1.3467x; 1.0106x over previous
//
#include <hip/hip_runtime.h>
#include <hip/hip_bf16.h>
#include <cstdint>
#include <cstddef>

// ---------------------------------------------------------------------------
// DisentangledMultiHeadAttention: B=8, H=2, T=2048, D=2048, C=4096
// FINAL (R15/R19 engine, thrice-reproduced at 2697-2704us) + merged 4-way
// input conversion (x, Wq, Wk, Wv in ONE launch; Wo separate -- its dest
// buf0 holds xb until the projections complete).
// GEMM engine: 256x256 tile, 8 waves (2Mx4N), 16x16x32 bf16 MFMA, 4-slot
// K=32 LDS ring (128KB), single barrier/slab, counted vmcnt(4) (never 0
// mid-loop), register prefetch of slab p+1 frags, SGB fine interleave
// 12x{1 DS_READ, 2 MFMA}+{8 MFMA}, frag-major 1KB LDS units (0 bank
// conflicts both sides), T1 XCD swizzle, T5 setprio, plain stores.
// Bracketed-and-rejected over 18 rounds: 32x32 MFMA (R10/R18 both orders),
// 128^2 tile (R16: HBM-bound), 4/16-wave variants (R9/R11), 8-phase ports
// (R5/R6), NT stores (write amplification), fused QKV (L3 thrash).
// Measured: proj GEMM ~525us (~1030 TF, 41% of dense peak -- structure
// ceiling, not a HW roofline), MfmaUtil 55%.
// v stored TRANSPOSED so PV is NT; softmax emits bf16 probs for PV.
// ---------------------------------------------------------------------------

typedef short short8_t __attribute__((ext_vector_type(8)));
typedef float f32x4   __attribute__((ext_vector_type(4)));

__device__ __forceinline__ short f2bf(float f) {
  unsigned u = __builtin_bit_cast(unsigned, f);
  u = (u + 0x7FFFu + ((u >> 16) & 1u)) >> 16;   // round-to-nearest-even
  return (short)u;
}

__device__ __forceinline__ short8_t cvt8(f32x4 a, f32x4 b) {
  short8_t r;
  r[0] = f2bf(a[0]); r[1] = f2bf(a[1]); r[2] = f2bf(a[2]); r[3] = f2bf(a[3]);
  r[4] = f2bf(b[0]); r[5] = f2bf(b[1]); r[6] = f2bf(b[2]); r[7] = f2bf(b[3]);
  return r;
}

__device__ __forceinline__ void gld_lds16(const void* g, void* l) {
  __builtin_amdgcn_global_load_lds(
      (const __attribute__((address_space(1))) void*)g,
      (__attribute__((address_space(3))) void*)l, 16, 0, 0);
}

// fp32 -> bf16 bulk convert; NT loads (fp32 source dead after this)
__global__ __launch_bounds__(256)
void cvt_f32_bf16(const float* __restrict__ src, short* __restrict__ dst, int n8) {
  for (int i = blockIdx.x * blockDim.x + threadIdx.x; i < n8;
       i += gridDim.x * blockDim.x) {
    const f32x4* p = (const f32x4*)(src + (size_t)i * 8);
    f32x4 a = __builtin_nontemporal_load(p);
    f32x4 b = __builtin_nontemporal_load(p + 1);
    *(short8_t*)(dst + (size_t)i * 8) = cvt8(a, b);
  }
}

// x + Wq + Wk + Wv -> xb + wqkv (single launch; all streaming, NT loads)
__global__ __launch_bounds__(256)
void cvt_all(const float* __restrict__ x,  const float* __restrict__ wq,
             const float* __restrict__ wk, const float* __restrict__ wv,
             short* __restrict__ xb, short* __restrict__ wqkv) {
  constexpr int NX = 67108864 / 8;   // x chunks (8 elems each)
  constexpr int NW = 16777216 / 8;   // per-W chunks
  constexpr int TOTAL = NX + 3 * NW;
  for (int i = blockIdx.x * blockDim.x + threadIdx.x; i < TOTAL;
       i += gridDim.x * blockDim.x) {
    const float* s;
    short* d;
    size_t off;
    if (i < NX) {
      s = x; d = xb; off = i;
    } else {
      const int j     = i - NX;
      const int which = j / NW;
      off = j - which * NW;
      s = (which == 0) ? wq : (which == 1) ? wk : wv;
      d = wqkv + (size_t)which * 16777216;
    }
    const f32x4* p = (const f32x4*)(s + off * 8);
    f32x4 a = __builtin_nontemporal_load(p);
    f32x4 b = __builtin_nontemporal_load(p + 1);
    *(short8_t*)(d + off * 8) = cvt8(a, b);
  }
}

// MODE 0: q/k proj  C=bf16 (b,h,t,d)                 K=4096
// MODE 2: v proj    C=bf16 (b,h,d,s) [transposed]    K=4096
// MODE 3: scores    C=f32 scale+bias -> attn (d_out) K=2048, batched z
// MODE 4: PV        C=bf16 (b*T+t, h*D+d)            K=2048, batched z
// MODE 5: out proj  C=f32 y (d_out)                  K=4096
template<int MODE>
__global__ __launch_bounds__(512, 2)
void gemm256(const short* __restrict__ Ag, const short* __restrict__ Bg,
             void* __restrict__ Cg, const float* __restrict__ bias) {
  constexpr int K  = (MODE == 3 || MODE == 4) ? 2048 : 4096;
  constexpr int NS = K / 32;   // K-slabs (even, >= 64)

  __shared__ short lds[65536];  // 4 slots x (A 8192 + B 8192 shorts) = 128KB

  const int tid = threadIdx.x;

  // T1: bijective XCD swizzle (gridDim.x = 1024, divisible by 8)
  const int bid = blockIdx.x;
  const int id  = (bid & 7) * (gridDim.x >> 3) + (bid >> 3);

  int m0, n0, z = 0;
  size_t aoff = 0, boff = 0;
  if constexpr (MODE == 3 || MODE == 4) {
    z  = id >> 6;                       // 16 batches
    m0 = ((id >> 3) & 7) << 8;          // 8 m-tiles
    n0 = (id & 7) << 8;                 // 8 n-tiles
    aoff = boff = (size_t)z << 22;
  } else {
    m0 = (id >> 4) << 8;                // 64 m-tiles
    n0 = (id & 15) << 8;                // 16 n-tiles (n fastest: A-panel reuse)
  }

  // ---- staging: slab = 1024 chunks of 16B; thread does chunks tid, tid+512
  //      per operand. chunk c -> row c>>2, phys slot c&3; global source slot
  //      = phys ^ ((row>>1)&3)  [inverse swizzle, both-sides rule].
  const int r0 = tid >> 2;
  const int qs = ((tid & 3) ^ ((r0 >> 1) & 3)) << 3;
  const short* Ap0 = Ag + aoff + (size_t)(m0 + r0) * K + qs;
  const short* Ap1 = Ap0 + (size_t)128 * K;
  const short* Bp0 = Bg + boff + (size_t)(n0 + r0) * K + qs;
  const short* Bp1 = Bp0 + (size_t)128 * K;
  short* la0 = &lds[0]    + tid * 8;
  short* la1 = la0 + 4096;
  short* lb0 = &lds[8192] + tid * 8;
  short* lb1 = lb0 + 4096;

  auto STAGE = [&](int t) {
    const int s = (t & 3) * 16384;
    const int k = t * 32;
    gld_lds16(Ap0 + k, la0 + s);
    gld_lds16(Ap1 + k, la1 + s);
    gld_lds16(Bp0 + k, lb0 + s);
    gld_lds16(Bp1 + k, lb1 + s);
  };

  // ---- fragment read setup (2-way-conflict swizzled; measured 0) ----
  const int l  = tid & 63;
  const int fr = l & 15;
  const int kq = l >> 4;
  const int wm = (tid >> 8) << 7;         // wave m offset: 0 / 128
  const int wn = ((tid >> 6) & 3) << 6;   // wave n offset: 0/64/128/192
  const int slotP = (kq ^ ((fr >> 1) & 3)) << 3;
  const int aB = (wm + fr) * 32 + slotP;
  const int bB = 8192 + (wn + fr) * 32 + slotP;

  f32x4 acc[8][4] = {};
  short8_t fA[8], fB[4], gA[8], gB[4];

  // Branch-free interleaved phase (valid for p <= NS-4): reads of slab p+1
  // interleaved 1:2 with slab-p MFMAs via sched_group_barrier.
  auto phaseF = [&](int p, short8_t (&cA)[8], short8_t (&cB)[4],
                    short8_t (&nA)[8], short8_t (&nB)[4]) {
    asm volatile("s_waitcnt vmcnt(4)" ::: "memory");   // slab p+1 landed
    __builtin_amdgcn_s_barrier();
    STAGE(p + 3);
    const short* sl = &lds[((p + 1) & 3) * 16384];
    __builtin_amdgcn_s_setprio(1);
#pragma unroll
    for (int gq = 0; gq < 4; ++gq) {
      nA[2 * gq]     = *(const short8_t*)&sl[aB + (2 * gq) * 512];
      nA[2 * gq + 1] = *(const short8_t*)&sl[aB + (2 * gq + 1) * 512];
      nB[gq]         = *(const short8_t*)&sl[bB + gq * 512];
#pragma unroll
      for (int mm = 0; mm < 2; ++mm)
#pragma unroll
        for (int n = 0; n < 4; ++n)
          acc[2 * gq + mm][n] = __builtin_amdgcn_mfma_f32_16x16x32_bf16(
              cA[2 * gq + mm], cB[n], acc[2 * gq + mm][n], 0, 0, 0);
    }
    // T19 fine-grain: 12 x {1 DS_READ, 2 MFMA} then {8 MFMA} tail.
    // (masks: DS_READ=0x100, MFMA=0x8); other classes unconstrained.
#pragma unroll
    for (int u = 0; u < 12; ++u) {
      __builtin_amdgcn_sched_group_barrier(0x100, 1, 0);
      __builtin_amdgcn_sched_group_barrier(0x008, 2, 0);
    }
    __builtin_amdgcn_sched_group_barrier(0x008, 8, 0);
    __builtin_amdgcn_s_setprio(0);
  };

  // Generic (branchy) phase -- used for the 4 tail phases.
  auto phaseT = [&](int p, short8_t (&cA)[8], short8_t (&cB)[4],
                    short8_t (&nA)[8], short8_t (&nB)[4]) {
    if (p + 2 < NS) {
      asm volatile("s_waitcnt vmcnt(4)" ::: "memory");
    } else {
      asm volatile("s_waitcnt vmcnt(0)" ::: "memory");
    }
    __builtin_amdgcn_s_barrier();
    if (p + 3 < NS) STAGE(p + 3);
    if (p + 1 < NS) {
      const short* sl = &lds[((p + 1) & 3) * 16384];
#pragma unroll
      for (int m = 0; m < 8; ++m) nA[m] = *(const short8_t*)&sl[aB + m * 512];
#pragma unroll
      for (int n = 0; n < 4; ++n) nB[n] = *(const short8_t*)&sl[bB + n * 512];
    }
    __builtin_amdgcn_s_setprio(1);
#pragma unroll
    for (int m = 0; m < 8; ++m)
#pragma unroll
      for (int n = 0; n < 4; ++n)
        acc[m][n] = __builtin_amdgcn_mfma_f32_16x16x32_bf16(cA[m], cB[n], acc[m][n], 0, 0, 0);
    __builtin_amdgcn_s_setprio(0);
  };

  STAGE(0); STAGE(1); STAGE(2);
  asm volatile("s_waitcnt vmcnt(8)" ::: "memory");   // slab 0 landed
  __builtin_amdgcn_s_barrier();
  {
    const short* sl = &lds[0];
#pragma unroll
    for (int m = 0; m < 8; ++m) fA[m] = *(const short8_t*)&sl[aB + m * 512];
#pragma unroll
    for (int n = 0; n < 4; ++n) fB[n] = *(const short8_t*)&sl[bB + n * 512];
  }

  int p = 0;
  for (; p < NS - 4; p += 2) {
    phaseF(p,     fA, fB, gA, gB);
    phaseF(p + 1, gA, gB, fA, fB);
  }
  // tail: phases NS-4 .. NS-1 (NS even -> cur = fA at NS-4)
  phaseT(NS - 4, fA, fB, gA, gB);
  phaseT(NS - 3, gA, gB, fA, fB);
  phaseT(NS - 2, fA, fB, gA, gB);
  phaseT(NS - 1, gA, gB, fA, fB);

  // ---- epilogue (plain stores): C/D layout col=lane&15, row=(l>>4)*4+r ----
#pragma unroll
  for (int m = 0; m < 8; ++m) {
#pragma unroll
    for (int n = 0; n < 4; ++n) {
#pragma unroll
      for (int r = 0; r < 4; ++r) {
        const int gm = m0 + wm + m * 16 + kq * 4 + r;
        const int gn = n0 + wn + n * 16 + fr;
        const float v = acc[m][n][r];
        if constexpr (MODE == 0) {
          short* dst = (short*)Cg;
          const int bh = ((gm >> 11) << 1) + (gn >> 11);
          dst[((size_t)bh << 22) + ((size_t)(gm & 2047) << 11) + (gn & 2047)] = f2bf(v);
        } else if constexpr (MODE == 2) {
          short* dst = (short*)Cg;
          const int bh = ((gm >> 11) << 1) + (gn >> 11);
          dst[((size_t)bh << 22) + ((size_t)(gn & 2047) << 11) + (gm & 2047)] = f2bf(v);
        } else if constexpr (MODE == 3) {
          float* dst = (float*)Cg;
          const float sv = v * 0.022097086912079608f + bias[((z & 1) << 11) + gn];
          dst[((size_t)z << 22) + ((size_t)gm << 11) + gn] = sv;
        } else if constexpr (MODE == 4) {
          short* dst = (short*)Cg;
          const size_t row = ((size_t)(z >> 1) << 11) + gm;
          dst[(row << 12) + ((size_t)(z & 1) << 11) + gn] = f2bf(v);
        } else {
          float* dst = (float*)Cg;
          dst[(size_t)gm * 4096 + gn] = v;
        }
      }
    }
  }
}

// row softmax in place (fp32, 2048 wide) + bf16 copy for the PV GEMM.
__global__ __launch_bounds__(256)
void softmax_rows(float* __restrict__ attn, short* __restrict__ outb) {
  float* row  = attn + ((size_t)blockIdx.x << 11);
  short* rowb = outb + ((size_t)blockIdx.x << 11);
  const int tid = threadIdx.x;

  f32x4 v0 = *(const f32x4*)(row + tid * 8);
  f32x4 v1 = *(const f32x4*)(row + tid * 8 + 4);

  float m = fmaxf(fmaxf(fmaxf(v0[0], v0[1]), fmaxf(v0[2], v0[3])),
                  fmaxf(fmaxf(v1[0], v1[1]), fmaxf(v1[2], v1[3])));
#pragma unroll
  for (int off = 1; off < 64; off <<= 1) m = fmaxf(m, __shfl_xor(m, off));

  __shared__ float redm[4];
  __shared__ float reds[4];
  if ((tid & 63) == 0) redm[tid >> 6] = m;
  __syncthreads();
  m = fmaxf(fmaxf(redm[0], redm[1]), fmaxf(redm[2], redm[3]));

  float e[8];
#pragma unroll
  for (int i = 0; i < 4; ++i) e[i]     = expf(v0[i] - m);
#pragma unroll
  for (int i = 0; i < 4; ++i) e[4 + i] = expf(v1[i] - m);
  float s = 0.f;
#pragma unroll
  for (int i = 0; i < 8; ++i) s += e[i];
#pragma unroll
  for (int off = 1; off < 64; off <<= 1) s += __shfl_xor(s, off);
  if ((tid & 63) == 0) reds[tid >> 6] = s;
  __syncthreads();
  s = reds[0] + reds[1] + reds[2] + reds[3];

  const float inv = 1.0f / s;
  f32x4 o0, o1;
#pragma unroll
  for (int i = 0; i < 4; ++i) { o0[i] = e[i] * inv; o1[i] = e[4 + i] * inv; }
  *(f32x4*)(row + tid * 8)     = o0;
  *(f32x4*)(row + tid * 8 + 4) = o1;
  *(short8_t*)(rowb + tid * 8) = cvt8(o0, o1);
}

extern "C" void kernel_launch(void* const* d_in, const int* in_sizes, int n_in,
                              void* d_out, int out_size, void* d_ws, size_t ws_size,
                              hipStream_t stream) {
  const float* x  = (const float*)d_in[0];
  const float* Wq = (const float*)d_in[1];
  const float* Wk = (const float*)d_in[2];
  const float* Wv = (const float*)d_in[3];
  const float* Wo = (const float*)d_in[4];
  const float* pb = (const float*)d_in[5];

  float* y_out = (float*)d_out;                       // 8*2048*4096 f32
  float* attn  = y_out + (size_t)8 * 2048 * 4096;     // 16*2048*2048 f32

  const size_t NEED = 4ull * 67108864ull * 2ull;      // 512 MB
  if (ws_size < NEED) return;
  short* buf0 = (short*)d_ws;
  short* buf1 = buf0 + 67108864;
  short* buf2 = buf1 + 67108864;
  short* buf3 = buf2 + 67108864;

  short* xb      = buf0;             // x bf16 (16384 x 4096)
  short* qb      = buf1;             // (b,h,t,d)
  short* kb      = buf2;             // (b,h,t,d)
  short* vtb     = buf3;             // (b,h,d,s)
  short* wob     = buf0;             // Wo bf16 (reuses xb after projections)
  short* attn_bf = buf1;             // bf16 probs (reuses qb after scores)
  short* yb      = buf2;             // attn@v bf16 (reuses kb after scores)
  short* wqkv    = (short*)attn;     // [Wq;Wk;Wv] bf16 (96 MB) in d_out attn
                                     // region (dead until scores GEMM)

  const dim3 blk512(512);
  const dim3 blk(256);
  const dim3 gcv(2048);
  const dim3 g1k(1024);

  cvt_all<<<gcv, blk, 0, stream>>>(x, Wq, Wk, Wv, xb, wqkv);

  gemm256<0><<<g1k, blk512, 0, stream>>>(xb, wqkv,                qb,  nullptr);
  gemm256<0><<<g1k, blk512, 0, stream>>>(xb, wqkv + 16777216,     kb,  nullptr);
  gemm256<2><<<g1k, blk512, 0, stream>>>(xb, wqkv + 2 * 16777216, vtb, nullptr);

  cvt_f32_bf16<<<gcv, blk, 0, stream>>>(Wo, wob, 16777216 / 8);  // x dead now

  gemm256<3><<<g1k, blk512, 0, stream>>>(qb, kb, attn, pb);
  softmax_rows<<<dim3(32768), blk, 0, stream>>>(attn, attn_bf);
  gemm256<4><<<g1k, blk512, 0, stream>>>(attn_bf, vtb, yb, nullptr);
  gemm256<5><<<g1k, blk512, 0, stream>>>(yb, wob, y_out, nullptr);
}